// Round 6
// baseline (170.158 us; speedup 1.0000x reference)
//
#include <hip/hip_runtime.h>
#include <stdint.h>

#define B_DIM 4096
#define I_DIM 1024
#define O_DIM 1024
#define KD    4096             // i*4 + (k-1): basis col k=0 is identically 0 for x in [0,1)
#define OUT_N (B_DIM * O_DIM)  // 4,194,304

#define SPLITK 4
#define KCHUNK (KD / SPLITK)   // 1024
#define NKT    (KCHUNK / 64)   // 16 K-tiles of 64

typedef short v8s __attribute__((ext_vector_type(8)));
typedef float v4f __attribute__((ext_vector_type(4)));

__device__ __forceinline__ uint16_t f2bf(float f) {
    union { float f; uint32_t u; } v; v.f = f;
    uint32_t u = v.u;
    return (uint16_t)((u + 0x7FFFu + ((u >> 16) & 1u)) >> 16);  // RNE
}
__device__ __forceinline__ float bf2f(uint32_t hi_bits) {
    union { uint32_t u; float f; } v; v.u = hi_bits; return v.f;
}

__device__ __forceinline__ void gload_lds16(const uint16_t* g, uint16_t* l) {
    __builtin_amdgcn_global_load_lds(
        (const __attribute__((address_space(1))) void*)g,
        (__attribute__((address_space(3))) void*)l,
        16, 0, 0);
}

// ---------------- zero d_out (atomic-fallback path only) ----------------
__global__ void zero_kernel(float4* __restrict__ out, int n4) {
    int idx = blockIdx.x * blockDim.x + threadIdx.x;
    if (idx < n4) out[idx] = float4{0.f, 0.f, 0.f, 0.f};
}

// ---------------- fused prep ----------------
// blocks 0..511:   basis  -> A[b][i*4+kk] (8 b-rows x 1024 i per block)
// blocks 512..639: wprep  -> WT[o][i*4+kk] = imp[i,o]*coeffs[i,o,kk+1]
// block  640:      zero the 64 splitK finisher counters
__global__ void prep_kernel(const float* __restrict__ x,
                            const float* __restrict__ coeffs,
                            const float* __restrict__ imp,
                            uint16_t* __restrict__ A, uint16_t* __restrict__ WT,
                            int* __restrict__ cnt) {
    __shared__ __align__(16) char lds[65536];   // used by wprep branch only
    int id = blockIdx.x;
    int t  = threadIdx.x;
    if (id < 512) {
        // ---- basis (closed form, uniform cubic B-spline) ----
        int b0 = id * 8;
#pragma unroll
        for (int bb = 0; bb < 8; ++bb) {
            int b = b0 + bb;
#pragma unroll
            for (int q = 0; q < 4; ++q) {
                int i = q * 256 + t;
                float xv = x[(size_t)b * I_DIM + i];
                float tt = 4.0f * xv;
                float fj = floorf(tt);
                fj = fminf(fmaxf(fj, 0.0f), 3.0f);
                int j4 = (int)fj;
                float u  = tt - fj;
                float um = 1.0f - u;
                float u2 = u * u, u3 = u2 * u;
                const float s = 1.0f / 6.0f;
                float w0 = um * um * um * s;
                float w1 = (3.0f * u3 - 6.0f * u2 + 4.0f) * s;
                float w2 = (-3.0f * u3 + 3.0f * u2 + 3.0f * u + 1.0f) * s;
                float w3 = u3 * s;
                float o0 = (j4 == 0) ? w0 : 0.0f;
                float o1 = (j4 == 0) ? w1 : (j4 == 1) ? w0 : 0.0f;
                float o2 = (j4 == 0) ? w2 : (j4 == 1) ? w1 : (j4 == 2) ? w0 : 0.0f;
                float o3 = (j4 == 0) ? w3 : (j4 == 1) ? w2 : (j4 == 2) ? w1 : w0;
                union { uint16_t h[4]; uint2 v; } pk;
                pk.h[0] = f2bf(o0); pk.h[1] = f2bf(o1);
                pk.h[2] = f2bf(o2); pk.h[3] = f2bf(o3);
                *(uint2*)(A + (size_t)b * KD + (size_t)i * 4) = pk.v;
            }
        }
    } else if (id < 640) {
        // ---- wprep with LDS transpose ----
        int bid = id - 512;
        int i0 = (bid & 31) * 32;        // i-slab
        int o0 = (bid >> 5) * 256;       // o-slab
        int o  = o0 + t;
        const int swz = (t & 7) << 4;
        union { uint16_t h[8]; uint4 v; } pk;
#pragma unroll
        for (int ii = 0; ii < 32; ++ii) {
            int i = i0 + ii;
            float im = imp[(size_t)i * O_DIM + o];
            const float* cp = coeffs + ((size_t)i * O_DIM + o) * 5;
            int base = (ii & 1) * 4;
            pk.h[base + 0] = f2bf(im * cp[1]);
            pk.h[base + 1] = f2bf(im * cp[2]);
            pk.h[base + 2] = f2bf(im * cp[3]);
            pk.h[base + 3] = f2bf(im * cp[4]);
            if (ii & 1)
                *(uint4*)(lds + t * 256 + (((ii - 1) * 8) ^ swz)) = pk.v;
        }
        __syncthreads();
#pragma unroll
        for (int j = 0; j < 16; ++j) {
            int c   = t + 256 * j;
            int row = c >> 4;
            int u   = c & 15;
            uint4 v = *(const uint4*)(lds + row * 256 + ((u * 16) ^ ((row & 7) << 4)));
            *(uint4*)(WT + (size_t)(o0 + row) * KD + i0 * 4 + u * 8) = v;
        }
    } else {
        if (t < 64) cnt[t] = 0;
    }
}

// ---------------- 8-phase 256x256 GEMM (T1..T5), splitK=4 + in-kernel finisher ----------------
// LDS halves: [128 rows][64 k] bf16, row stride 128B, XOR-swizzle byte^=((row&7)<<4).

template<int RH>
__device__ __forceinline__ void read_half_a(const uint16_t* base, int lane, v8s (&f)[4][2]) {
    const char* b = (const char*)base;
    const int swz = (lane & 7) << 4;
    const int kb0 = (lane >> 4) << 4;
    const int lr0 = RH * 64 + (lane & 15);
#pragma unroll
    for (int mb = 0; mb < 4; ++mb)
#pragma unroll
        for (int ks = 0; ks < 2; ++ks)
            f[mb][ks] = *(const v8s*)(b + (size_t)(lr0 + mb * 16) * 128 + ((kb0 + ks * 64) ^ swz));
}

template<int CH>
__device__ __forceinline__ void read_half_b(const uint16_t* base, int lane, int wchalf,
                                            v8s (&f)[2][2]) {
    const char* b = (const char*)base;
    const int swz = (lane & 7) << 4;
    const int kb0 = (lane >> 4) << 4;
    const int lo0 = wchalf + CH * 32 + (lane & 15);
#pragma unroll
    for (int nb = 0; nb < 2; ++nb)
#pragma unroll
        for (int ks = 0; ks < 2; ++ks)
            f[nb][ks] = *(const v8s*)(b + (size_t)(lo0 + nb * 16) * 128 + ((kb0 + ks * 64) ^ swz));
}

__device__ __forceinline__ void mma_q(const v8s (&a)[4][2], const v8s (&bq)[2][2],
                                      v4f (&ac)[4][2]) {
    __builtin_amdgcn_s_setprio(1);
#pragma unroll
    for (int mb = 0; mb < 4; ++mb)
#pragma unroll
        for (int nb = 0; nb < 2; ++nb)
#pragma unroll
            for (int ks = 0; ks < 2; ++ks)
                ac[mb][nb] = __builtin_amdgcn_mfma_f32_16x16x32_bf16(a[mb][ks], bq[nb][ks],
                                                                     ac[mb][nb], 0, 0, 0);
    __builtin_amdgcn_s_setprio(0);
}

template<int PARTIAL>
__global__ __launch_bounds__(512, 2)
void gemm_kernel(const uint16_t* __restrict__ A, const uint16_t* __restrict__ WT,
                 float* __restrict__ out, uint16_t* __restrict__ P, int* __restrict__ cnt) {
    // T1: XCD-chunked block swizzle (256 blocks, 32/XCD)
    int hw  = blockIdx.x;
    int lid = (hw & 7) * 32 + (hw >> 3);
    int nt = lid & 3, mt = (lid >> 2) & 15, sk = lid >> 6;

    int t    = threadIdx.x;
    int lane = t & 63;
    int wid  = t >> 6;
    int wr = wid >> 2, wc = wid & 3;           // 2 x 4 wave grid; wave owns 128x64

    __shared__ uint16_t sA[2][2][128 * 64];
    __shared__ uint16_t sB[2][2][128 * 64];

    const uint16_t* Ab = A  + (size_t)(mt * 256) * KD + sk * KCHUNK;
    const uint16_t* Bb = WT + (size_t)(nt * 256) * KD + sk * KCHUNK;

    const int r0  = t >> 3;
    const int kel = ((((t & 7) << 4) ^ ((r0 & 7) << 4)) >> 1);

    auto stageA = [&](int buf, int half, int kt) {
        const uint16_t* g = Ab + (size_t)(half * 128 + r0) * KD + kt * 64 + kel;
        gload_lds16(g,                   &sA[buf][half][t * 8]);
        gload_lds16(g + (size_t)64 * KD, &sA[buf][half][4096 + t * 8]);
    };
    auto stageB = [&](int buf, int half, int kt) {
        const uint16_t* g = Bb + (size_t)(half * 128 + r0) * KD + kt * 64 + kel;
        gload_lds16(g,                   &sB[buf][half][t * 8]);
        gload_lds16(g + (size_t)64 * KD, &sB[buf][half][4096 + t * 8]);
    };

    v8s af[4][2], bf0[2][2], bf1[2][2];
    v4f a00[4][2] = {}, a01[4][2] = {}, a10[4][2] = {}, a11[4][2] = {};

    const int wch = (wc & 1) * 64;
    const int bh  = wc >> 1;

    stageB(0, 0, 0); stageB(0, 1, 0);
    stageA(0, 0, 0); stageA(0, 1, 0);
    stageB(1, 0, 1); stageB(1, 1, 1);
    asm volatile("s_waitcnt vmcnt(4)" ::: "memory");
    __builtin_amdgcn_s_barrier();

#pragma unroll 2
    for (int g = 0; g < NKT; ++g) {
        const int buf = g & 1, nbuf = buf ^ 1;
        read_half_a<0>(&sA[buf][wr][0], lane, af);
        read_half_b<0>(&sB[buf][bh][0], lane, wch, bf0);
        if (g + 1 < NKT) stageA(nbuf, 0, g + 1);
        __builtin_amdgcn_s_barrier();
        asm volatile("s_waitcnt lgkmcnt(0)" ::: "memory");
        mma_q(af, bf0, a00);
        __builtin_amdgcn_s_barrier();

        read_half_b<1>(&sB[buf][bh][0], lane, wch, bf1);
        if (g + 1 < NKT) stageA(nbuf, 1, g + 1);
        __builtin_amdgcn_s_barrier();
        asm volatile("s_waitcnt lgkmcnt(0)" ::: "memory");
        mma_q(af, bf1, a01);
        __builtin_amdgcn_s_barrier();

        read_half_a<1>(&sA[buf][wr][0], lane, af);
        if (g + 2 < NKT) stageB(buf, 0, g + 2);
        __builtin_amdgcn_s_barrier();
        asm volatile("s_waitcnt lgkmcnt(0)" ::: "memory");
        mma_q(af, bf0, a10);
        __builtin_amdgcn_s_barrier();

        if (g + 2 < NKT) stageB(buf, 1, g + 2);
        __builtin_amdgcn_s_barrier();
        mma_q(af, bf1, a11);
        if (g < NKT - 2)       asm volatile("s_waitcnt vmcnt(4)" ::: "memory");
        else if (g == NKT - 2) asm volatile("s_waitcnt vmcnt(0)" ::: "memory");
        __builtin_amdgcn_s_barrier();
    }

    const int oc  = lane & 15;
    const int orr = (lane >> 4) * 4;
    if (PARTIAL) {
        // ---- every sk-block writes bf16 partials ----
        uint16_t* pb = P + (size_t)sk * OUT_N
                         + (size_t)(mt * 256 + wr * 128) * O_DIM + nt * 256 + wc * 64;
#pragma unroll
        for (int mb = 0; mb < 4; ++mb)
#pragma unroll
            for (int nb = 0; nb < 2; ++nb)
#pragma unroll
                for (int r = 0; r < 4; ++r) {
                    pb[(size_t)(mb * 16 + orr + r) * O_DIM + nb * 16 + oc]           = f2bf(a00[mb][nb][r]);
                    pb[(size_t)(mb * 16 + orr + r) * O_DIM + 32 + nb * 16 + oc]      = f2bf(a01[mb][nb][r]);
                    pb[(size_t)(64 + mb * 16 + orr + r) * O_DIM + nb * 16 + oc]      = f2bf(a10[mb][nb][r]);
                    pb[(size_t)(64 + mb * 16 + orr + r) * O_DIM + 32 + nb * 16 + oc] = f2bf(a11[mb][nb][r]);
                }
        // ---- last sk-block per (mt,nt) tile reduces all 4 partials ----
        __threadfence();                              // device-scope release
        __shared__ int is_last;
        if (t == 0) {
            int old = atomicAdd(&cnt[mt * 4 + nt], 1);
            is_last = (old == SPLITK - 1);
        }
        __syncthreads();
        if (is_last) {
            __threadfence();                          // device-scope acquire
            // tile = 256x256 at (mt*256, nt*256); 512 threads x 16 iters x 8 elems
            const size_t tbase = (size_t)(mt * 256) * O_DIM + nt * 256;
#pragma unroll 4
            for (int j = 0; j < 16; ++j) {
                int e   = (j * 512 + t) * 8;
                int row = e >> 8;
                int col = e & 255;
                size_t off = tbase + (size_t)row * O_DIM + col;
                float s[8] = {0, 0, 0, 0, 0, 0, 0, 0};
#pragma unroll
                for (int s2 = 0; s2 < SPLITK; ++s2) {
                    uint4 v = *(const uint4*)(P + (size_t)s2 * OUT_N + off);
                    uint32_t w[4] = {v.x, v.y, v.z, v.w};
#pragma unroll
                    for (int q = 0; q < 4; ++q) {
                        s[2 * q]     += bf2f((w[q] & 0xFFFFu) << 16);
                        s[2 * q + 1] += bf2f(w[q] & 0xFFFF0000u);
                    }
                }
                float4 lo = {s[0], s[1], s[2], s[3]};
                float4 hi = {s[4], s[5], s[6], s[7]};
                *(float4*)(out + off)     = lo;
                *(float4*)(out + off + 4) = hi;
            }
        }
    } else {
        float* ob = out + (size_t)(mt * 256 + wr * 128) * O_DIM + nt * 256 + wc * 64;
#pragma unroll
        for (int mb = 0; mb < 4; ++mb)
#pragma unroll
            for (int nb = 0; nb < 2; ++nb)
#pragma unroll
                for (int r = 0; r < 4; ++r) {
                    atomicAdd(&ob[(size_t)(mb * 16 + orr + r) * O_DIM + nb * 16 + oc],           a00[mb][nb][r]);
                    atomicAdd(&ob[(size_t)(mb * 16 + orr + r) * O_DIM + 32 + nb * 16 + oc],      a01[mb][nb][r]);
                    atomicAdd(&ob[(size_t)(64 + mb * 16 + orr + r) * O_DIM + nb * 16 + oc],      a10[mb][nb][r]);
                    atomicAdd(&ob[(size_t)(64 + mb * 16 + orr + r) * O_DIM + 32 + nb * 16 + oc], a11[mb][nb][r]);
                }
    }
}

extern "C" void kernel_launch(void* const* d_in, const int* in_sizes, int n_in,
                              void* d_out, int out_size, void* d_ws, size_t ws_size,
                              hipStream_t stream) {
    const float* x      = (const float*)d_in[0];
    const float* coeffs = (const float*)d_in[1];
    const float* imp    = (const float*)d_in[2];
    float* out = (float*)d_out;

    const size_t A_ELEMS  = (size_t)B_DIM * KD;          // 16,777,216 (33.6 MB)
    const size_t WT_ELEMS = (size_t)O_DIM * KD;          //  4,194,304 ( 8.4 MB)
    const size_t P_ELEMS  = (size_t)SPLITK * OUT_N;      // 16,777,216 (33.6 MB)
    uint16_t* A  = (uint16_t*)d_ws;
    uint16_t* WT = A + A_ELEMS;
    uint16_t* P  = WT + WT_ELEMS;
    int*      cnt = (int*)(P + P_ELEMS);
    const size_t need = (A_ELEMS + WT_ELEMS + P_ELEMS) * 2 + 64 * 4;   // ~75.5 MB

    hipLaunchKernelGGL(prep_kernel, dim3(512 + 128 + 1), dim3(256), 0, stream,
                       x, coeffs, imp, A, WT, cnt);
    if (ws_size >= need) {
        hipLaunchKernelGGL((gemm_kernel<1>), dim3(256), dim3(512), 0, stream, A, WT, out, P, cnt);
    } else {
        hipLaunchKernelGGL(zero_kernel, dim3((OUT_N / 4) / 256), dim3(256), 0, stream,
                           (float4*)out, OUT_N / 4);
        hipLaunchKernelGGL((gemm_kernel<0>), dim3(256), dim3(512), 0, stream, A, WT, out, P, cnt);
    }
}

// Round 7
// 66.284 us; speedup vs baseline: 2.5671x; 2.5671x over previous
//
#include <hip/hip_runtime.h>
#include <stdint.h>

#define B_DIM 4096
#define I_DIM 1024
#define O_DIM 1024
#define KD    4096             // i*4 + (k-1): basis col k=0 is identically 0 for x in [0,1)
#define OUT_N (B_DIM * O_DIM)  // 4,194,304

#define SPLITK 2
#define KCHUNK (KD / SPLITK)   // 2048
#define NKT    (KCHUNK / 64)   // 32 K-tiles of 64

typedef short v8s __attribute__((ext_vector_type(8)));
typedef float v4f __attribute__((ext_vector_type(4)));

__device__ __forceinline__ uint16_t f2bf(float f) {
    union { float f; uint32_t u; } v; v.f = f;
    uint32_t u = v.u;
    return (uint16_t)((u + 0x7FFFu + ((u >> 16) & 1u)) >> 16);  // RNE
}
__device__ __forceinline__ float bf2f(uint32_t hi_bits) {
    union { uint32_t u; float f; } v; v.u = hi_bits; return v.f;
}

__device__ __forceinline__ void gload_lds16(const uint16_t* g, uint16_t* l) {
    __builtin_amdgcn_global_load_lds(
        (const __attribute__((address_space(1))) void*)g,
        (__attribute__((address_space(3))) void*)l,
        16, 0, 0);
}

// ---------------- zero d_out (atomic-fallback path only) ----------------
__global__ void zero_kernel(float4* __restrict__ out, int n4) {
    int idx = blockIdx.x * blockDim.x + threadIdx.x;
    if (idx < n4) out[idx] = float4{0.f, 0.f, 0.f, 0.f};
}

// ---------------- fused prep ----------------
// blocks 0..511:   basis  -> A[b][i*4+kk] (8 b-rows x 1024 i per block)
// blocks 512..639: wprep  -> WT[o][i*4+kk] = imp[i,o]*coeffs[i,o,kk+1]
__global__ void prep_kernel(const float* __restrict__ x,
                            const float* __restrict__ coeffs,
                            const float* __restrict__ imp,
                            uint16_t* __restrict__ A, uint16_t* __restrict__ WT) {
    __shared__ __align__(16) char lds[65536];   // used by wprep branch only
    int id = blockIdx.x;
    int t  = threadIdx.x;
    if (id < 512) {
        // ---- basis (closed form, uniform cubic B-spline) ----
        int b0 = id * 8;
#pragma unroll
        for (int bb = 0; bb < 8; ++bb) {
            int b = b0 + bb;
#pragma unroll
            for (int q = 0; q < 4; ++q) {
                int i = q * 256 + t;
                float xv = x[(size_t)b * I_DIM + i];
                float tt = 4.0f * xv;
                float fj = floorf(tt);
                fj = fminf(fmaxf(fj, 0.0f), 3.0f);
                int j4 = (int)fj;
                float u  = tt - fj;
                float um = 1.0f - u;
                float u2 = u * u, u3 = u2 * u;
                const float s = 1.0f / 6.0f;
                float w0 = um * um * um * s;
                float w1 = (3.0f * u3 - 6.0f * u2 + 4.0f) * s;
                float w2 = (-3.0f * u3 + 3.0f * u2 + 3.0f * u + 1.0f) * s;
                float w3 = u3 * s;
                float o0 = (j4 == 0) ? w0 : 0.0f;
                float o1 = (j4 == 0) ? w1 : (j4 == 1) ? w0 : 0.0f;
                float o2 = (j4 == 0) ? w2 : (j4 == 1) ? w1 : (j4 == 2) ? w0 : 0.0f;
                float o3 = (j4 == 0) ? w3 : (j4 == 1) ? w2 : (j4 == 2) ? w1 : w0;
                union { uint16_t h[4]; uint2 v; } pk;
                pk.h[0] = f2bf(o0); pk.h[1] = f2bf(o1);
                pk.h[2] = f2bf(o2); pk.h[3] = f2bf(o3);
                *(uint2*)(A + (size_t)b * KD + (size_t)i * 4) = pk.v;
            }
        }
    } else {
        // ---- wprep with LDS transpose ----
        int bid = id - 512;
        int i0 = (bid & 31) * 32;        // i-slab
        int o0 = (bid >> 5) * 256;       // o-slab
        int o  = o0 + t;
        const int swz = (t & 7) << 4;
        union { uint16_t h[8]; uint4 v; } pk;
#pragma unroll
        for (int ii = 0; ii < 32; ++ii) {
            int i = i0 + ii;
            float im = imp[(size_t)i * O_DIM + o];
            const float* cp = coeffs + ((size_t)i * O_DIM + o) * 5;
            int base = (ii & 1) * 4;
            pk.h[base + 0] = f2bf(im * cp[1]);
            pk.h[base + 1] = f2bf(im * cp[2]);
            pk.h[base + 2] = f2bf(im * cp[3]);
            pk.h[base + 3] = f2bf(im * cp[4]);
            if (ii & 1)
                *(uint4*)(lds + t * 256 + (((ii - 1) * 8) ^ swz)) = pk.v;
        }
        __syncthreads();
#pragma unroll
        for (int j = 0; j < 16; ++j) {
            int c   = t + 256 * j;
            int row = c >> 4;
            int u   = c & 15;
            uint4 v = *(const uint4*)(lds + row * 256 + ((u * 16) ^ ((row & 7) << 4)));
            *(uint4*)(WT + (size_t)(o0 + row) * KD + i0 * 4 + u * 8) = v;
        }
    }
}

// ---------------- GEMM: 256x128 tile, splitK=2, 2-phase/K-tile, counted vmcnt ----------------
// LDS: A halves [128 rows][64 k], B halves [64 rows][64 k]; row stride 128B,
// XOR-swizzle byte^=((row&7)<<4) (T2), inverse-swizzled global source (rule 21).

template<int RH>
__device__ __forceinline__ void read_half_a(const uint16_t* base, int lane, v8s (&f)[4][2]) {
    const char* b = (const char*)base;
    const int swz = (lane & 7) << 4;
    const int kb0 = (lane >> 4) << 4;
    const int lr0 = RH * 64 + (lane & 15);
#pragma unroll
    for (int mb = 0; mb < 4; ++mb)
#pragma unroll
        for (int ks = 0; ks < 2; ++ks)
            f[mb][ks] = *(const v8s*)(b + (size_t)(lr0 + mb * 16) * 128 + ((kb0 + ks * 64) ^ swz));
}

__device__ __forceinline__ void read_b(const uint16_t* base, int lane, int wch, v8s (&f)[2][2]) {
    const char* b = (const char*)base;
    const int swz = (lane & 7) << 4;
    const int kb0 = (lane >> 4) << 4;
    const int lo0 = wch + (lane & 15);
#pragma unroll
    for (int nb = 0; nb < 2; ++nb)
#pragma unroll
        for (int ks = 0; ks < 2; ++ks)
            f[nb][ks] = *(const v8s*)(b + (size_t)(lo0 + nb * 16) * 128 + ((kb0 + ks * 64) ^ swz));
}

__device__ __forceinline__ void mma_q(const v8s (&a)[4][2], const v8s (&bq)[2][2],
                                      v4f (&ac)[4][2]) {
    __builtin_amdgcn_s_setprio(1);
#pragma unroll
    for (int mb = 0; mb < 4; ++mb)
#pragma unroll
        for (int nb = 0; nb < 2; ++nb)
#pragma unroll
            for (int ks = 0; ks < 2; ++ks)
                ac[mb][nb] = __builtin_amdgcn_mfma_f32_16x16x32_bf16(a[mb][ks], bq[nb][ks],
                                                                     ac[mb][nb], 0, 0, 0);
    __builtin_amdgcn_s_setprio(0);
}

template<int PARTIAL>
__global__ __launch_bounds__(512, 2)
void gemm_kernel(const uint16_t* __restrict__ A, const uint16_t* __restrict__ WT,
                 float* __restrict__ out, uint16_t* __restrict__ P) {
    // T1: XCD-chunked block swizzle; nt (A-panel sharers) clustered per XCD
    int hw  = blockIdx.x;
    int lid = (hw & 7) * 32 + (hw >> 3);
    int nt = lid & 7, mt = (lid >> 3) & 15, sk = lid >> 7;

    int t    = threadIdx.x;
    int lane = t & 63;
    int wid  = t >> 6;
    int wr = wid >> 2, wc = wid & 3;           // 2 x 4 wave grid; wave owns 128 x 32

    __shared__ uint16_t sA[2][2][128 * 64];    // 64 KB
    __shared__ uint16_t sB[2][2][64 * 64];     // 32 KB

    const uint16_t* Ab = A  + (size_t)(mt * 256) * KD + sk * KCHUNK;
    const uint16_t* Bb = WT + (size_t)(nt * 128) * KD + sk * KCHUNK;

    const int r0  = t >> 3;                    // [0,64)
    const int kel = ((((t & 7) << 4) ^ ((r0 & 7) << 4)) >> 1);

    auto stageA = [&](int buf, int half, int kt) {       // 128-row half: 2 gloads
        const uint16_t* g = Ab + (size_t)(half * 128 + r0) * KD + kt * 64 + kel;
        gload_lds16(g,                   &sA[buf][half][t * 8]);
        gload_lds16(g + (size_t)64 * KD, &sA[buf][half][4096 + t * 8]);
    };
    auto stageB = [&](int buf, int half, int kt) {       // 64-row half: 1 gload
        const uint16_t* g = Bb + (size_t)(half * 64 + r0) * KD + kt * 64 + kel;
        gload_lds16(g, &sB[buf][half][t * 8]);
    };

    v8s af[4][2], bf[2][2];
    v4f aq0[4][2] = {}, aq1[4][2] = {};

    const int wch = (wc & 1) * 32;   // B local-row offset within its 64-row half
    const int bh  = wc >> 1;         // B half index for this wave

    // ---- prologue: B(0), A(0), B(1); wait A(0)+B(0), leave B(1) in flight ----
    stageB(0, 0, 0); stageB(0, 1, 0);
    stageA(0, 0, 0); stageA(0, 1, 0);
    stageB(1, 0, 1); stageB(1, 1, 1);
    asm volatile("s_waitcnt vmcnt(2)" ::: "memory");
    __builtin_amdgcn_s_barrier();

#pragma unroll 2
    for (int g = 0; g < NKT; ++g) {
        const int buf = g & 1, nbuf = buf ^ 1;
        // ---- p1: read A-rh0 (8) + B (4); stage A(g+1) (4 gloads) ----
        read_half_a<0>(&sA[buf][wr][0], lane, af);
        read_b(&sB[buf][bh][0], lane, wch, bf);
        if (g + 1 < NKT) { stageA(nbuf, 0, g + 1); stageA(nbuf, 1, g + 1); }
        __builtin_amdgcn_s_barrier();
        asm volatile("s_waitcnt lgkmcnt(0)" ::: "memory");
        mma_q(af, bf, aq0);
        __builtin_amdgcn_s_barrier();
        // ---- p2: read A-rh1 (8); stage B(g+2) (2 gloads, same-parity buf) ----
        read_half_a<1>(&sA[buf][wr][0], lane, af);
        if (g + 2 < NKT) { stageB(buf, 0, g + 2); stageB(buf, 1, g + 2); }
        __builtin_amdgcn_s_barrier();
        asm volatile("s_waitcnt lgkmcnt(0)" ::: "memory");
        mma_q(af, bf, aq1);
        // boundary: in flight = A(g+1) x4 + B(g+2) x2 -> retire A(g+1); never 0 mid-loop
        if (g < NKT - 2)       asm volatile("s_waitcnt vmcnt(2)" ::: "memory");
        else if (g == NKT - 2) asm volatile("s_waitcnt vmcnt(0)" ::: "memory");
        __builtin_amdgcn_s_barrier();
    }

    // ---- epilogue (C/D layout: col=lane&15, row=(lane>>4)*4+r) ----
    const int oc  = lane & 15;
    const int orr = (lane >> 4) * 4;
    if (PARTIAL) {
        uint16_t* pb = P + (size_t)sk * OUT_N
                         + (size_t)(mt * 256 + wr * 128) * O_DIM + nt * 128 + wc * 32;
#pragma unroll
        for (int mb = 0; mb < 4; ++mb)
#pragma unroll
            for (int nb = 0; nb < 2; ++nb)
#pragma unroll
                for (int r = 0; r < 4; ++r) {
                    pb[(size_t)(mb * 16 + orr + r) * O_DIM + nb * 16 + oc]      = f2bf(aq0[mb][nb][r]);
                    pb[(size_t)(64 + mb * 16 + orr + r) * O_DIM + nb * 16 + oc] = f2bf(aq1[mb][nb][r]);
                }
    } else {
        float* ob = out + (size_t)(mt * 256 + wr * 128) * O_DIM + nt * 128 + wc * 32;
#pragma unroll
        for (int mb = 0; mb < 4; ++mb)
#pragma unroll
            for (int nb = 0; nb < 2; ++nb)
#pragma unroll
                for (int r = 0; r < 4; ++r) {
                    atomicAdd(&ob[(size_t)(mb * 16 + orr + r) * O_DIM + nb * 16 + oc],      aq0[mb][nb][r]);
                    atomicAdd(&ob[(size_t)(64 + mb * 16 + orr + r) * O_DIM + nb * 16 + oc], aq1[mb][nb][r]);
                }
    }
}

// ---------------- reduce: out[j] = sum_sk bf2f(P[sk][j]) ----------------
__global__ void reduce_kernel(const uint16_t* __restrict__ P, float* __restrict__ out) {
    size_t idx = ((size_t)blockIdx.x * 256 + threadIdx.x) * 8;
    float s[8] = {0, 0, 0, 0, 0, 0, 0, 0};
#pragma unroll
    for (int sk = 0; sk < SPLITK; ++sk) {
        uint4 v = *(const uint4*)(P + (size_t)sk * OUT_N + idx);
        uint32_t w[4] = {v.x, v.y, v.z, v.w};
#pragma unroll
        for (int j = 0; j < 4; ++j) {
            s[2 * j]     += bf2f((w[j] & 0xFFFFu) << 16);
            s[2 * j + 1] += bf2f(w[j] & 0xFFFF0000u);
        }
    }
    float4 lo = {s[0], s[1], s[2], s[3]};
    float4 hi = {s[4], s[5], s[6], s[7]};
    *(float4*)(out + idx)     = lo;
    *(float4*)(out + idx + 4) = hi;
}

extern "C" void kernel_launch(void* const* d_in, const int* in_sizes, int n_in,
                              void* d_out, int out_size, void* d_ws, size_t ws_size,
                              hipStream_t stream) {
    const float* x      = (const float*)d_in[0];
    const float* coeffs = (const float*)d_in[1];
    const float* imp    = (const float*)d_in[2];
    float* out = (float*)d_out;

    const size_t A_ELEMS  = (size_t)B_DIM * KD;          // 16,777,216 (33.6 MB)
    const size_t WT_ELEMS = (size_t)O_DIM * KD;          //  4,194,304 ( 8.4 MB)
    const size_t P_ELEMS  = (size_t)SPLITK * OUT_N;      //  8,388,608 (16.8 MB)
    uint16_t* A  = (uint16_t*)d_ws;
    uint16_t* WT = A + A_ELEMS;
    uint16_t* P  = WT + WT_ELEMS;
    const size_t need = (A_ELEMS + WT_ELEMS + P_ELEMS) * 2;   // ~58.7 MB

    hipLaunchKernelGGL(prep_kernel, dim3(512 + 128), dim3(256), 0, stream,
                       x, coeffs, imp, A, WT);
    if (ws_size >= need) {
        hipLaunchKernelGGL((gemm_kernel<1>), dim3(256), dim3(512), 0, stream, A, WT, out, P);
        hipLaunchKernelGGL(reduce_kernel, dim3(OUT_N / 8 / 256), dim3(256), 0, stream, P, out);
    } else {
        hipLaunchKernelGGL(zero_kernel, dim3((OUT_N / 4) / 256), dim3(256), 0, stream,
                           (float4*)out, OUT_N / 4);
        hipLaunchKernelGGL((gemm_kernel<0>), dim3(256), dim3(512), 0, stream, A, WT, out, P);
    }
}

// Round 8
// 63.027 us; speedup vs baseline: 2.6998x; 1.0517x over previous
//
#include <hip/hip_runtime.h>
#include <stdint.h>

#define B_DIM 4096
#define I_DIM 1024
#define O_DIM 1024
#define KD    4096             // i*4 + (k-1): basis col k=0 is identically 0 for x in [0,1)
#define OUT_N (B_DIM * O_DIM)  // 4,194,304

#define SPLITK 4
#define KCHUNK (KD / SPLITK)   // 1024
#define NKT    (KCHUNK / 64)   // 16 K-tiles of 64

typedef short v8s __attribute__((ext_vector_type(8)));
typedef float v4f __attribute__((ext_vector_type(4)));

__device__ __forceinline__ uint16_t f2bf(float f) {
    union { float f; uint32_t u; } v; v.f = f;
    uint32_t u = v.u;
    return (uint16_t)((u + 0x7FFFu + ((u >> 16) & 1u)) >> 16);  // RNE
}
__device__ __forceinline__ float bf2f(uint32_t hi_bits) {
    union { uint32_t u; float f; } v; v.u = hi_bits; return v.f;
}

__device__ __forceinline__ void gload_lds16(const uint16_t* g, uint16_t* l) {
    __builtin_amdgcn_global_load_lds(
        (const __attribute__((address_space(1))) void*)g,
        (__attribute__((address_space(3))) void*)l,
        16, 0, 0);
}

// ---------------- zero d_out (atomic-fallback path only) ----------------
__global__ void zero_kernel(float4* __restrict__ out, int n4) {
    int idx = blockIdx.x * blockDim.x + threadIdx.x;
    if (idx < n4) out[idx] = float4{0.f, 0.f, 0.f, 0.f};
}

// ---------------- fused prep ----------------
// blocks 0..511:   basis  -> A[b][i*4+kk] (8 b-rows x 1024 i per block)
// blocks 512..639: wprep  -> WT[o][i*4+kk] = imp[i,o]*coeffs[i,o,kk+1]
__global__ void prep_kernel(const float* __restrict__ x,
                            const float* __restrict__ coeffs,
                            const float* __restrict__ imp,
                            uint16_t* __restrict__ A, uint16_t* __restrict__ WT) {
    __shared__ __align__(16) char lds[65536];   // used by wprep branch only
    int id = blockIdx.x;
    int t  = threadIdx.x;
    if (id < 512) {
        // ---- basis (closed form, uniform cubic B-spline) ----
        int b0 = id * 8;
#pragma unroll
        for (int bb = 0; bb < 8; ++bb) {
            int b = b0 + bb;
#pragma unroll
            for (int q = 0; q < 4; ++q) {
                int i = q * 256 + t;
                float xv = x[(size_t)b * I_DIM + i];
                float tt = 4.0f * xv;
                float fj = floorf(tt);
                fj = fminf(fmaxf(fj, 0.0f), 3.0f);
                int j4 = (int)fj;
                float u  = tt - fj;
                float um = 1.0f - u;
                float u2 = u * u, u3 = u2 * u;
                const float s = 1.0f / 6.0f;
                float w0 = um * um * um * s;
                float w1 = (3.0f * u3 - 6.0f * u2 + 4.0f) * s;
                float w2 = (-3.0f * u3 + 3.0f * u2 + 3.0f * u + 1.0f) * s;
                float w3 = u3 * s;
                float o0 = (j4 == 0) ? w0 : 0.0f;
                float o1 = (j4 == 0) ? w1 : (j4 == 1) ? w0 : 0.0f;
                float o2 = (j4 == 0) ? w2 : (j4 == 1) ? w1 : (j4 == 2) ? w0 : 0.0f;
                float o3 = (j4 == 0) ? w3 : (j4 == 1) ? w2 : (j4 == 2) ? w1 : w0;
                union { uint16_t h[4]; uint2 v; } pk;
                pk.h[0] = f2bf(o0); pk.h[1] = f2bf(o1);
                pk.h[2] = f2bf(o2); pk.h[3] = f2bf(o3);
                *(uint2*)(A + (size_t)b * KD + (size_t)i * 4) = pk.v;
            }
        }
    } else {
        // ---- wprep with LDS transpose ----
        int bid = id - 512;
        int i0 = (bid & 31) * 32;        // i-slab
        int o0 = (bid >> 5) * 256;       // o-slab
        int o  = o0 + t;
        const int swz = (t & 7) << 4;
        union { uint16_t h[8]; uint4 v; } pk;
#pragma unroll
        for (int ii = 0; ii < 32; ++ii) {
            int i = i0 + ii;
            float im = imp[(size_t)i * O_DIM + o];
            const float* cp = coeffs + ((size_t)i * O_DIM + o) * 5;
            int base = (ii & 1) * 4;
            pk.h[base + 0] = f2bf(im * cp[1]);
            pk.h[base + 1] = f2bf(im * cp[2]);
            pk.h[base + 2] = f2bf(im * cp[3]);
            pk.h[base + 3] = f2bf(im * cp[4]);
            if (ii & 1)
                *(uint4*)(lds + t * 256 + (((ii - 1) * 8) ^ swz)) = pk.v;
        }
        __syncthreads();
#pragma unroll
        for (int j = 0; j < 16; ++j) {
            int c   = t + 256 * j;
            int row = c >> 4;
            int u   = c & 15;
            uint4 v = *(const uint4*)(lds + row * 256 + ((u * 16) ^ ((row & 7) << 4)));
            *(uint4*)(WT + (size_t)(o0 + row) * KD + i0 * 4 + u * 8) = v;
        }
    }
}

// ---------------- 8-phase 256x256 GEMM (T1..T5), splitK=4, coalesced epilogue ----------------
// LDS halves: [128 rows][64 k] bf16, row stride 128B, XOR-swizzle byte^=((row&7)<<4).

template<int RH>
__device__ __forceinline__ void read_half_a(const uint16_t* base, int lane, v8s (&f)[4][2]) {
    const char* b = (const char*)base;
    const int swz = (lane & 7) << 4;
    const int kb0 = (lane >> 4) << 4;
    const int lr0 = RH * 64 + (lane & 15);
#pragma unroll
    for (int mb = 0; mb < 4; ++mb)
#pragma unroll
        for (int ks = 0; ks < 2; ++ks)
            f[mb][ks] = *(const v8s*)(b + (size_t)(lr0 + mb * 16) * 128 + ((kb0 + ks * 64) ^ swz));
}

template<int CH>
__device__ __forceinline__ void read_half_b(const uint16_t* base, int lane, int wchalf,
                                            v8s (&f)[2][2]) {
    const char* b = (const char*)base;
    const int swz = (lane & 7) << 4;
    const int kb0 = (lane >> 4) << 4;
    const int lo0 = wchalf + CH * 32 + (lane & 15);
#pragma unroll
    for (int nb = 0; nb < 2; ++nb)
#pragma unroll
        for (int ks = 0; ks < 2; ++ks)
            f[nb][ks] = *(const v8s*)(b + (size_t)(lo0 + nb * 16) * 128 + ((kb0 + ks * 64) ^ swz));
}

__device__ __forceinline__ void mma_q(const v8s (&a)[4][2], const v8s (&bq)[2][2],
                                      v4f (&ac)[4][2]) {
    __builtin_amdgcn_s_setprio(1);
#pragma unroll
    for (int mb = 0; mb < 4; ++mb)
#pragma unroll
        for (int nb = 0; nb < 2; ++nb)
#pragma unroll
            for (int ks = 0; ks < 2; ++ks)
                ac[mb][nb] = __builtin_amdgcn_mfma_f32_16x16x32_bf16(a[mb][ks], bq[nb][ks],
                                                                     ac[mb][nb], 0, 0, 0);
    __builtin_amdgcn_s_setprio(0);
}

template<int PARTIAL>
__global__ __launch_bounds__(512, 2)
void gemm_kernel(const uint16_t* __restrict__ A, const uint16_t* __restrict__ WT,
                 float* __restrict__ out, uint16_t* __restrict__ P) {
    // T1: XCD-chunked block swizzle (256 blocks, 32/XCD)
    int hw  = blockIdx.x;
    int lid = (hw & 7) * 32 + (hw >> 3);
    int nt = lid & 3, mt = (lid >> 2) & 15, sk = lid >> 6;

    int t    = threadIdx.x;
    int lane = t & 63;
    int wid  = t >> 6;
    int wr = wid >> 2, wc = wid & 3;           // 2 x 4 wave grid; wave owns 128x64

    __shared__ __align__(16) uint16_t smem[65536];          // 128 KB flat
    auto sAp = [&](int buf, int half) { return smem + (buf * 2 + half) * 8192; };
    auto sBp = [&](int buf, int half) { return smem + 32768 + (buf * 2 + half) * 8192; };

    const uint16_t* Ab = A  + (size_t)(mt * 256) * KD + sk * KCHUNK;
    const uint16_t* Bb = WT + (size_t)(nt * 256) * KD + sk * KCHUNK;

    const int r0  = t >> 3;
    const int kel = ((((t & 7) << 4) ^ ((r0 & 7) << 4)) >> 1);

    auto stageA = [&](int buf, int half, int kt) {
        const uint16_t* g = Ab + (size_t)(half * 128 + r0) * KD + kt * 64 + kel;
        uint16_t* l = sAp(buf, half);
        gload_lds16(g,                   l + t * 8);
        gload_lds16(g + (size_t)64 * KD, l + 4096 + t * 8);
    };
    auto stageB = [&](int buf, int half, int kt) {
        const uint16_t* g = Bb + (size_t)(half * 128 + r0) * KD + kt * 64 + kel;
        uint16_t* l = sBp(buf, half);
        gload_lds16(g,                   l + t * 8);
        gload_lds16(g + (size_t)64 * KD, l + 4096 + t * 8);
    };

    v8s af[4][2], bf0[2][2], bf1[2][2];
    v4f a00[4][2] = {}, a01[4][2] = {}, a10[4][2] = {}, a11[4][2] = {};

    const int wch = (wc & 1) * 64;
    const int bh  = wc >> 1;

    stageB(0, 0, 0); stageB(0, 1, 0);
    stageA(0, 0, 0); stageA(0, 1, 0);
    stageB(1, 0, 1); stageB(1, 1, 1);
    asm volatile("s_waitcnt vmcnt(4)" ::: "memory");
    __builtin_amdgcn_s_barrier();

#pragma unroll 2
    for (int g = 0; g < NKT; ++g) {
        const int buf = g & 1, nbuf = buf ^ 1;
        read_half_a<0>(sAp(buf, wr), lane, af);
        read_half_b<0>(sBp(buf, bh), lane, wch, bf0);
        if (g + 1 < NKT) stageA(nbuf, 0, g + 1);
        __builtin_amdgcn_s_barrier();
        asm volatile("s_waitcnt lgkmcnt(0)" ::: "memory");
        mma_q(af, bf0, a00);
        __builtin_amdgcn_s_barrier();

        read_half_b<1>(sBp(buf, bh), lane, wch, bf1);
        if (g + 1 < NKT) stageA(nbuf, 1, g + 1);
        __builtin_amdgcn_s_barrier();
        asm volatile("s_waitcnt lgkmcnt(0)" ::: "memory");
        mma_q(af, bf1, a01);
        __builtin_amdgcn_s_barrier();

        read_half_a<1>(sAp(buf, wr), lane, af);
        if (g + 2 < NKT) stageB(buf, 0, g + 2);
        __builtin_amdgcn_s_barrier();
        asm volatile("s_waitcnt lgkmcnt(0)" ::: "memory");
        mma_q(af, bf0, a10);
        __builtin_amdgcn_s_barrier();

        if (g + 2 < NKT) stageB(buf, 1, g + 2);
        __builtin_amdgcn_s_barrier();
        mma_q(af, bf1, a11);
        if (g < NKT - 2)       asm volatile("s_waitcnt vmcnt(4)" ::: "memory");
        else if (g == NKT - 2) asm volatile("s_waitcnt vmcnt(0)" ::: "memory");
        __builtin_amdgcn_s_barrier();
    }
    // final barrier above: all waves done with sA/sB -> LDS reusable per-wave

    const int oc  = lane & 15;
    const int orr = (lane >> 4) * 4;
    if (PARTIAL) {
        // ---- coalesced epilogue: per-wave LDS transpose (16 KB private region) ----
        uint16_t* wlds = smem + wid * 8192;   // [128 rows][64 cols], elem ^= (row&7)<<3
#pragma unroll
        for (int mb = 0; mb < 4; ++mb)
#pragma unroll
            for (int nb = 0; nb < 2; ++nb)
#pragma unroll
                for (int r = 0; r < 4; ++r) {
                    int rowL = mb * 16 + orr + r, rowH = rowL + 64;
                    int colL = nb * 16 + oc,      colH = colL + 32;
                    int sL = (rowL & 7) << 3, sH = (rowH & 7) << 3;
                    wlds[rowL * 64 + (colL ^ sL)] = f2bf(a00[mb][nb][r]);
                    wlds[rowL * 64 + (colH ^ sL)] = f2bf(a01[mb][nb][r]);
                    wlds[rowH * 64 + (colL ^ sH)] = f2bf(a10[mb][nb][r]);
                    wlds[rowH * 64 + (colH ^ sH)] = f2bf(a11[mb][nb][r]);
                }
        asm volatile("s_waitcnt lgkmcnt(0)" ::: "memory");
        uint16_t* pb = P + (size_t)sk * OUT_N
                         + (size_t)(mt * 256 + wr * 128) * O_DIM + nt * 256 + wc * 64;
#pragma unroll 4
        for (int j = 0; j < 16; ++j) {
            int c   = j * 64 + lane;
            int row = c >> 3;
            int col = (c & 7) * 8;
            uint4 v = *(const uint4*)&wlds[row * 64 + (col ^ ((row & 7) << 3))];
            *(uint4*)(pb + (size_t)row * O_DIM + col) = v;
        }
    } else {
        float* ob = out + (size_t)(mt * 256 + wr * 128) * O_DIM + nt * 256 + wc * 64;
#pragma unroll
        for (int mb = 0; mb < 4; ++mb)
#pragma unroll
            for (int nb = 0; nb < 2; ++nb)
#pragma unroll
                for (int r = 0; r < 4; ++r) {
                    atomicAdd(&ob[(size_t)(mb * 16 + orr + r) * O_DIM + nb * 16 + oc],           a00[mb][nb][r]);
                    atomicAdd(&ob[(size_t)(mb * 16 + orr + r) * O_DIM + 32 + nb * 16 + oc],      a01[mb][nb][r]);
                    atomicAdd(&ob[(size_t)(64 + mb * 16 + orr + r) * O_DIM + nb * 16 + oc],      a10[mb][nb][r]);
                    atomicAdd(&ob[(size_t)(64 + mb * 16 + orr + r) * O_DIM + 32 + nb * 16 + oc], a11[mb][nb][r]);
                }
    }
}

// ---------------- reduce: out[j] = sum_sk bf2f(P[sk][j]) ----------------
__global__ void reduce_kernel(const uint16_t* __restrict__ P, float* __restrict__ out) {
    size_t idx = ((size_t)blockIdx.x * 256 + threadIdx.x) * 8;
    float s[8] = {0, 0, 0, 0, 0, 0, 0, 0};
#pragma unroll
    for (int sk = 0; sk < SPLITK; ++sk) {
        uint4 v = *(const uint4*)(P + (size_t)sk * OUT_N + idx);
        uint32_t w[4] = {v.x, v.y, v.z, v.w};
#pragma unroll
        for (int j = 0; j < 4; ++j) {
            s[2 * j]     += bf2f((w[j] & 0xFFFFu) << 16);
            s[2 * j + 1] += bf2f(w[j] & 0xFFFF0000u);
        }
    }
    float4 lo = {s[0], s[1], s[2], s[3]};
    float4 hi = {s[4], s[5], s[6], s[7]};
    *(float4*)(out + idx)     = lo;
    *(float4*)(out + idx + 4) = hi;
}

extern "C" void kernel_launch(void* const* d_in, const int* in_sizes, int n_in,
                              void* d_out, int out_size, void* d_ws, size_t ws_size,
                              hipStream_t stream) {
    const float* x      = (const float*)d_in[0];
    const float* coeffs = (const float*)d_in[1];
    const float* imp    = (const float*)d_in[2];
    float* out = (float*)d_out;

    const size_t A_ELEMS  = (size_t)B_DIM * KD;          // 16,777,216 (33.6 MB)
    const size_t WT_ELEMS = (size_t)O_DIM * KD;          //  4,194,304 ( 8.4 MB)
    const size_t P_ELEMS  = (size_t)SPLITK * OUT_N;      // 16,777,216 (33.6 MB)
    uint16_t* A  = (uint16_t*)d_ws;
    uint16_t* WT = A + A_ELEMS;
    uint16_t* P  = WT + WT_ELEMS;
    const size_t need = (A_ELEMS + WT_ELEMS + P_ELEMS) * 2;   // ~75.5 MB

    hipLaunchKernelGGL(prep_kernel, dim3(512 + 128), dim3(256), 0, stream,
                       x, coeffs, imp, A, WT);
    if (ws_size >= need) {
        hipLaunchKernelGGL((gemm_kernel<1>), dim3(256), dim3(512), 0, stream, A, WT, out, P);
        hipLaunchKernelGGL(reduce_kernel, dim3(OUT_N / 8 / 256), dim3(256), 0, stream, P, out);
    } else {
        hipLaunchKernelGGL(zero_kernel, dim3((OUT_N / 4) / 256), dim3(256), 0, stream,
                           (float4*)out, OUT_N / 4);
        hipLaunchKernelGGL((gemm_kernel<0>), dim3(256), dim3(512), 0, stream, A, WT, out, P);
    }
}

// Round 9
// 62.772 us; speedup vs baseline: 2.7108x; 1.0041x over previous
//
#include <hip/hip_runtime.h>
#include <stdint.h>

#define B_DIM 4096
#define I_DIM 1024
#define O_DIM 1024
#define KD    4096             // i*4 + (k-1): basis col k=0 is identically 0 for x in [0,1)
#define NKT   64               // K-tiles of 64, splitK=1

typedef short v8s __attribute__((ext_vector_type(8)));
typedef float v4f __attribute__((ext_vector_type(4)));

__device__ __forceinline__ uint16_t f2bf(float f) {
    union { float f; uint32_t u; } v; v.f = f;
    uint32_t u = v.u;
    return (uint16_t)((u + 0x7FFFu + ((u >> 16) & 1u)) >> 16);  // RNE
}

__device__ __forceinline__ void gload_lds16(const uint16_t* g, uint16_t* l) {
    __builtin_amdgcn_global_load_lds(
        (const __attribute__((address_space(1))) void*)g,
        (__attribute__((address_space(3))) void*)l,
        16, 0, 0);
}

// ---------------- fused prep ----------------
// blocks 0..511:   basis  -> A[b][i*4+kk] (8 b-rows x 1024 i per block)
// blocks 512..639: wprep  -> WT[o][i*4+kk] = imp[i,o]*coeffs[i,o,kk+1]
__global__ void prep_kernel(const float* __restrict__ x,
                            const float* __restrict__ coeffs,
                            const float* __restrict__ imp,
                            uint16_t* __restrict__ A, uint16_t* __restrict__ WT) {
    __shared__ __align__(16) char lds[65536];   // used by wprep branch only
    int id = blockIdx.x;
    int t  = threadIdx.x;
    if (id < 512) {
        // ---- basis (closed form, uniform cubic B-spline) ----
        int b0 = id * 8;
#pragma unroll
        for (int bb = 0; bb < 8; ++bb) {
            int b = b0 + bb;
#pragma unroll
            for (int q = 0; q < 4; ++q) {
                int i = q * 256 + t;
                float xv = x[(size_t)b * I_DIM + i];
                float tt = 4.0f * xv;
                float fj = floorf(tt);
                fj = fminf(fmaxf(fj, 0.0f), 3.0f);
                int j4 = (int)fj;
                float u  = tt - fj;
                float um = 1.0f - u;
                float u2 = u * u, u3 = u2 * u;
                const float s = 1.0f / 6.0f;
                float w0 = um * um * um * s;
                float w1 = (3.0f * u3 - 6.0f * u2 + 4.0f) * s;
                float w2 = (-3.0f * u3 + 3.0f * u2 + 3.0f * u + 1.0f) * s;
                float w3 = u3 * s;
                float o0 = (j4 == 0) ? w0 : 0.0f;
                float o1 = (j4 == 0) ? w1 : (j4 == 1) ? w0 : 0.0f;
                float o2 = (j4 == 0) ? w2 : (j4 == 1) ? w1 : (j4 == 2) ? w0 : 0.0f;
                float o3 = (j4 == 0) ? w3 : (j4 == 1) ? w2 : (j4 == 2) ? w1 : w0;
                union { uint16_t h[4]; uint2 v; } pk;
                pk.h[0] = f2bf(o0); pk.h[1] = f2bf(o1);
                pk.h[2] = f2bf(o2); pk.h[3] = f2bf(o3);
                *(uint2*)(A + (size_t)b * KD + (size_t)i * 4) = pk.v;
            }
        }
    } else {
        // ---- wprep with LDS transpose ----
        int bid = id - 512;
        int i0 = (bid & 31) * 32;        // i-slab
        int o0 = (bid >> 5) * 256;       // o-slab
        int o  = o0 + t;
        const int swz = (t & 7) << 4;
        union { uint16_t h[8]; uint4 v; } pk;
#pragma unroll
        for (int ii = 0; ii < 32; ++ii) {
            int i = i0 + ii;
            float im = imp[(size_t)i * O_DIM + o];
            const float* cp = coeffs + ((size_t)i * O_DIM + o) * 5;
            int base = (ii & 1) * 4;
            pk.h[base + 0] = f2bf(im * cp[1]);
            pk.h[base + 1] = f2bf(im * cp[2]);
            pk.h[base + 2] = f2bf(im * cp[3]);
            pk.h[base + 3] = f2bf(im * cp[4]);
            if (ii & 1)
                *(uint4*)(lds + t * 256 + (((ii - 1) * 8) ^ swz)) = pk.v;
        }
        __syncthreads();
#pragma unroll
        for (int j = 0; j < 16; ++j) {
            int c   = t + 256 * j;
            int row = c >> 4;
            int u   = c & 15;
            uint4 v = *(const uint4*)(lds + row * 256 + ((u * 16) ^ ((row & 7) << 4)));
            *(uint4*)(WT + (size_t)(o0 + row) * KD + i0 * 4 + u * 8) = v;
        }
    }
}

// ---------------- GEMM: 128x128 tile, splitK=1, 2 blocks/CU, m97-style loop ----------------
// LDS: A [128][64], B [128][64] bf16, double-buffered (64 KB total).
// Row stride 128B, XOR-swizzle byte^=((row&7)<<4) (T2), inverse-swizzled source (rule 21).

__global__ __launch_bounds__(512, 4)
void gemm_kernel(const uint16_t* __restrict__ A, const uint16_t* __restrict__ WT,
                 float* __restrict__ out) {
    // T1: XCD-chunked swizzle; each XCD gets 4 mt x 8 nt (A panels 4MB + B 8.4MB)
    int hw  = blockIdx.x;
    int lid = (hw & 7) * 32 + (hw >> 3);
    int nt = lid & 7, mt = lid >> 3;           // mt in [0,32), nt in [0,8)

    int t    = threadIdx.x;
    int lane = t & 63;
    int wid  = t >> 6;
    int wr = wid >> 2, wc = wid & 3;           // 2 x 4 wave grid; wave tile 64 x 32

    __shared__ __align__(16) uint16_t smem[32768];   // 64 KB flat
    uint16_t* sA0 = smem;                            // [buf][128][64] -> buf*8192
    uint16_t* sB0 = smem + 16384;

    const uint16_t* Ab = A  + (size_t)(mt * 128) * KD;
    const uint16_t* Bb = WT + (size_t)(nt * 128) * KD;

    const int r0  = t >> 3;                          // [0,64)
    const int kel = ((((t & 7) << 4) ^ ((r0 & 7) << 4)) >> 1);  // elems, 8-aligned

    auto stage = [&](int buf, int kt) {
        const uint16_t* ga = Ab + (size_t)r0 * KD + kt * 64 + kel;
        const uint16_t* gb = Bb + (size_t)r0 * KD + kt * 64 + kel;
        gload_lds16(ga,                   sA0 + buf * 8192 + t * 8);
        gload_lds16(ga + (size_t)64 * KD, sA0 + buf * 8192 + 4096 + t * 8);
        gload_lds16(gb,                   sB0 + buf * 8192 + t * 8);
        gload_lds16(gb + (size_t)64 * KD, sB0 + buf * 8192 + 4096 + t * 8);
    };

    v8s af[4][2], bf[2][2];
    v4f acc[4][2] = {};

    const int swz = (lane & 7) << 4;
    const int kb0 = (lane >> 4) << 4;
    const int lra = wr * 64 + (lane & 15);
    const int lrb = wc * 32 + (lane & 15);

    stage(0, 0);
    asm volatile("s_waitcnt vmcnt(0)" ::: "memory");
    __builtin_amdgcn_s_barrier();

#pragma unroll 2
    for (int g = 0; g < NKT; ++g) {
        const int buf = g & 1;
        if (g + 1 < NKT) stage(buf ^ 1, g + 1);

        const char* ba = (const char*)(sA0 + buf * 8192);
        const char* bb = (const char*)(sB0 + buf * 8192);
#pragma unroll
        for (int mb = 0; mb < 4; ++mb)
#pragma unroll
            for (int ks = 0; ks < 2; ++ks)
                af[mb][ks] = *(const v8s*)(ba + (size_t)(lra + mb * 16) * 128 + ((kb0 + ks * 64) ^ swz));
#pragma unroll
        for (int nb = 0; nb < 2; ++nb)
#pragma unroll
            for (int ks = 0; ks < 2; ++ks)
                bf[nb][ks] = *(const v8s*)(bb + (size_t)(lrb + nb * 16) * 128 + ((kb0 + ks * 64) ^ swz));

        asm volatile("s_waitcnt lgkmcnt(0)" ::: "memory");
        __builtin_amdgcn_s_setprio(1);
#pragma unroll
        for (int mb = 0; mb < 4; ++mb)
#pragma unroll
            for (int nb = 0; nb < 2; ++nb)
#pragma unroll
                for (int ks = 0; ks < 2; ++ks)
                    acc[mb][nb] = __builtin_amdgcn_mfma_f32_16x16x32_bf16(af[mb][ks], bf[nb][ks],
                                                                          acc[mb][nb], 0, 0, 0);
        __builtin_amdgcn_s_setprio(0);

        if (g + 1 < NKT) asm volatile("s_waitcnt vmcnt(0)" ::: "memory");
        __builtin_amdgcn_s_barrier();
    }

    // ---- epilogue: per-wave f32 LDS transpose (8 KB private), coalesced stores ----
    // C/D frag layout: col = lane&15, row = (lane>>4)*4 + r  [m89]
    float* wlds = (float*)smem + wid * 2048;        // [64][32] f32, XOR (((row>>2)&1)<<4)
    const int oc  = lane & 15;
    const int orr = (lane >> 4) * 4;
#pragma unroll
    for (int mb = 0; mb < 4; ++mb)
#pragma unroll
        for (int nb = 0; nb < 2; ++nb)
#pragma unroll
            for (int r = 0; r < 4; ++r) {
                int row = mb * 16 + orr + r;
                int col = nb * 16 + oc;
                wlds[row * 32 + (col ^ (((row >> 2) & 1) << 4))] = acc[mb][nb][r];
            }
    asm volatile("s_waitcnt lgkmcnt(0)" ::: "memory");   // wave-private region, no barrier
    float* ob = out + (size_t)(mt * 128 + wr * 64) * O_DIM + nt * 128 + wc * 32;
#pragma unroll
    for (int j = 0; j < 8; ++j) {
        int idx = j * 64 + lane;
        int row = idx >> 3;
        int qc  = (idx & 7) * 4;
        v4f v = *(const v4f*)&wlds[row * 32 + (qc ^ (((row >> 2) & 1) << 4))];
        *(float4*)(ob + (size_t)row * O_DIM + qc) = float4{v[0], v[1], v[2], v[3]};
    }
}

extern "C" void kernel_launch(void* const* d_in, const int* in_sizes, int n_in,
                              void* d_out, int out_size, void* d_ws, size_t ws_size,
                              hipStream_t stream) {
    const float* x      = (const float*)d_in[0];
    const float* coeffs = (const float*)d_in[1];
    const float* imp    = (const float*)d_in[2];
    float* out = (float*)d_out;

    const size_t A_ELEMS = (size_t)B_DIM * KD;   // 16,777,216 (33.6 MB bf16)
    uint16_t* A  = (uint16_t*)d_ws;
    uint16_t* WT = A + A_ELEMS;                  // 8.4 MB bf16

    hipLaunchKernelGGL(prep_kernel, dim3(512 + 128), dim3(256), 0, stream,
                       x, coeffs, imp, A, WT);
    hipLaunchKernelGGL(gemm_kernel, dim3(256), dim3(512), 0, stream, A, WT, out);
}

// Round 10
// 61.277 us; speedup vs baseline: 2.7769x; 1.0244x over previous
//
#include <hip/hip_runtime.h>
#include <stdint.h>

#define B_DIM 4096
#define I_DIM 1024
#define O_DIM 1024
#define KD    4096             // i*4 + (k-1): basis col k=0 is identically 0 for x in [0,1)
#define OUT_N (B_DIM * O_DIM)  // 4,194,304

#define SPLITK 2
#define KCHUNK (KD / SPLITK)   // 2048
#define NKT    (KCHUNK / 64)   // 32 K-tiles of 64

typedef short v8s __attribute__((ext_vector_type(8)));
typedef float v4f __attribute__((ext_vector_type(4)));

__device__ __forceinline__ uint16_t f2bf(float f) {
    union { float f; uint32_t u; } v; v.f = f;
    uint32_t u = v.u;
    return (uint16_t)((u + 0x7FFFu + ((u >> 16) & 1u)) >> 16);  // RNE
}
__device__ __forceinline__ float bf2f(uint32_t hi_bits) {
    union { uint32_t u; float f; } v; v.u = hi_bits; return v.f;
}

__device__ __forceinline__ void gload_lds16(const uint16_t* g, uint16_t* l) {
    __builtin_amdgcn_global_load_lds(
        (const __attribute__((address_space(1))) void*)g,
        (__attribute__((address_space(3))) void*)l,
        16, 0, 0);
}

// ---------------- zero d_out (atomic-fallback path only) ----------------
__global__ void zero_kernel(float4* __restrict__ out, int n4) {
    int idx = blockIdx.x * blockDim.x + threadIdx.x;
    if (idx < n4) out[idx] = float4{0.f, 0.f, 0.f, 0.f};
}

// ---------------- fused prep ----------------
// blocks 0..511:   basis  -> A[b][i*4+kk] (8 b-rows x 1024 i per block)
// blocks 512..639: wprep  -> WT[o][i*4+kk] = imp[i,o]*coeffs[i,o,kk+1]
__global__ void prep_kernel(const float* __restrict__ x,
                            const float* __restrict__ coeffs,
                            const float* __restrict__ imp,
                            uint16_t* __restrict__ A, uint16_t* __restrict__ WT) {
    __shared__ __align__(16) char lds[65536];   // used by wprep branch only
    int id = blockIdx.x;
    int t  = threadIdx.x;
    if (id < 512) {
        // ---- basis (closed form, uniform cubic B-spline) ----
        int b0 = id * 8;
#pragma unroll
        for (int bb = 0; bb < 8; ++bb) {
            int b = b0 + bb;
#pragma unroll
            for (int q = 0; q < 4; ++q) {
                int i = q * 256 + t;
                float xv = x[(size_t)b * I_DIM + i];
                float tt = 4.0f * xv;
                float fj = floorf(tt);
                fj = fminf(fmaxf(fj, 0.0f), 3.0f);
                int j4 = (int)fj;
                float u  = tt - fj;
                float um = 1.0f - u;
                float u2 = u * u, u3 = u2 * u;
                const float s = 1.0f / 6.0f;
                float w0 = um * um * um * s;
                float w1 = (3.0f * u3 - 6.0f * u2 + 4.0f) * s;
                float w2 = (-3.0f * u3 + 3.0f * u2 + 3.0f * u + 1.0f) * s;
                float w3 = u3 * s;
                float o0 = (j4 == 0) ? w0 : 0.0f;
                float o1 = (j4 == 0) ? w1 : (j4 == 1) ? w0 : 0.0f;
                float o2 = (j4 == 0) ? w2 : (j4 == 1) ? w1 : (j4 == 2) ? w0 : 0.0f;
                float o3 = (j4 == 0) ? w3 : (j4 == 1) ? w2 : (j4 == 2) ? w1 : w0;
                union { uint16_t h[4]; uint2 v; } pk;
                pk.h[0] = f2bf(o0); pk.h[1] = f2bf(o1);
                pk.h[2] = f2bf(o2); pk.h[3] = f2bf(o3);
                *(uint2*)(A + (size_t)b * KD + (size_t)i * 4) = pk.v;
            }
        }
    } else {
        // ---- wprep with LDS transpose ----
        int bid = id - 512;
        int i0 = (bid & 31) * 32;        // i-slab
        int o0 = (bid >> 5) * 256;       // o-slab
        int o  = o0 + t;
        const int swz = (t & 7) << 4;
        union { uint16_t h[8]; uint4 v; } pk;
#pragma unroll
        for (int ii = 0; ii < 32; ++ii) {
            int i = i0 + ii;
            float im = imp[(size_t)i * O_DIM + o];
            const float* cp = coeffs + ((size_t)i * O_DIM + o) * 5;
            int base = (ii & 1) * 4;
            pk.h[base + 0] = f2bf(im * cp[1]);
            pk.h[base + 1] = f2bf(im * cp[2]);
            pk.h[base + 2] = f2bf(im * cp[3]);
            pk.h[base + 3] = f2bf(im * cp[4]);
            if (ii & 1)
                *(uint4*)(lds + t * 256 + (((ii - 1) * 8) ^ swz)) = pk.v;
        }
        __syncthreads();
#pragma unroll
        for (int j = 0; j < 16; ++j) {
            int c   = t + 256 * j;
            int row = c >> 4;
            int u   = c & 15;
            uint4 v = *(const uint4*)(lds + row * 256 + ((u * 16) ^ ((row & 7) << 4)));
            *(uint4*)(WT + (size_t)(o0 + row) * KD + i0 * 4 + u * 8) = v;
        }
    }
}

// ---------------- GEMM: 128x128 tile, splitK=2, 2 blocks/CU co-resident ----------------
// LDS: A [128][64], B [128][64] bf16, double-buffered (64 KB -> 2 blocks/CU).
// Row stride 128B, XOR-swizzle byte^=((row&7)<<4) (T2), inverse-swizzled source (rule 21).

template<int PARTIAL>
__global__ __launch_bounds__(512, 4)
void gemm_kernel(const uint16_t* __restrict__ A, const uint16_t* __restrict__ WT,
                 float* __restrict__ out, uint16_t* __restrict__ P) {
    // T1: XCD-chunked swizzle; each XCD chunk of 64 = 4 mt x 2 sk x 8 nt (panel L2 reuse)
    int hw  = blockIdx.x;
    int lid = (hw & 7) * 64 + (hw >> 3);
    int nt = lid & 7, sk = (lid >> 3) & 1, mt = lid >> 4;   // mt [0,32), nt [0,8), sk [0,2)

    int t    = threadIdx.x;
    int lane = t & 63;
    int wid  = t >> 6;
    int wr = wid >> 2, wc = wid & 3;           // 2 x 4 wave grid; wave tile 64 x 32

    __shared__ __align__(16) uint16_t smem[32768];   // 64 KB flat
    uint16_t* sA0 = smem;                            // [buf][128][64] -> buf*8192
    uint16_t* sB0 = smem + 16384;

    const uint16_t* Ab = A  + (size_t)(mt * 128) * KD + sk * KCHUNK;
    const uint16_t* Bb = WT + (size_t)(nt * 128) * KD + sk * KCHUNK;

    const int r0  = t >> 3;                          // [0,64)
    const int kel = ((((t & 7) << 4) ^ ((r0 & 7) << 4)) >> 1);  // elems, 8-aligned

    auto stage = [&](int buf, int kt) {
        const uint16_t* ga = Ab + (size_t)r0 * KD + kt * 64 + kel;
        const uint16_t* gb = Bb + (size_t)r0 * KD + kt * 64 + kel;
        gload_lds16(ga,                   sA0 + buf * 8192 + t * 8);
        gload_lds16(ga + (size_t)64 * KD, sA0 + buf * 8192 + 4096 + t * 8);
        gload_lds16(gb,                   sB0 + buf * 8192 + t * 8);
        gload_lds16(gb + (size_t)64 * KD, sB0 + buf * 8192 + 4096 + t * 8);
    };

    v8s af[4][2], bf[2][2];
    v4f acc[4][2] = {};

    const int swz = (lane & 7) << 4;
    const int kb0 = (lane >> 4) << 4;
    const int lra = wr * 64 + (lane & 15);
    const int lrb = wc * 32 + (lane & 15);

    stage(0, 0);
    asm volatile("s_waitcnt vmcnt(0)" ::: "memory");
    __builtin_amdgcn_s_barrier();

#pragma unroll 2
    for (int g = 0; g < NKT; ++g) {
        const int buf = g & 1;
        if (g + 1 < NKT) stage(buf ^ 1, g + 1);

        const char* ba = (const char*)(sA0 + buf * 8192);
        const char* bb = (const char*)(sB0 + buf * 8192);
#pragma unroll
        for (int mb = 0; mb < 4; ++mb)
#pragma unroll
            for (int ks = 0; ks < 2; ++ks)
                af[mb][ks] = *(const v8s*)(ba + (size_t)(lra + mb * 16) * 128 + ((kb0 + ks * 64) ^ swz));
#pragma unroll
        for (int nb = 0; nb < 2; ++nb)
#pragma unroll
            for (int ks = 0; ks < 2; ++ks)
                bf[nb][ks] = *(const v8s*)(bb + (size_t)(lrb + nb * 16) * 128 + ((kb0 + ks * 64) ^ swz));

        asm volatile("s_waitcnt lgkmcnt(0)" ::: "memory");
        __builtin_amdgcn_s_setprio(1);
#pragma unroll
        for (int mb = 0; mb < 4; ++mb)
#pragma unroll
            for (int nb = 0; nb < 2; ++nb)
#pragma unroll
                for (int ks = 0; ks < 2; ++ks)
                    acc[mb][nb] = __builtin_amdgcn_mfma_f32_16x16x32_bf16(af[mb][ks], bf[nb][ks],
                                                                          acc[mb][nb], 0, 0, 0);
        __builtin_amdgcn_s_setprio(0);

        if (g + 1 < NKT) asm volatile("s_waitcnt vmcnt(0)" ::: "memory");
        __builtin_amdgcn_s_barrier();
    }

    // ---- epilogue (C/D layout: col=lane&15, row=(lane>>4)*4+r) ----
    const int oc  = lane & 15;
    const int orr = (lane >> 4) * 4;
    if (PARTIAL) {
        // wave-private LDS transpose [64][32] bf16 (2 KB... 4 KB region), coalesced stores
        uint16_t* wlds = smem + wid * 2048;          // [64 rows][32 cols]
#pragma unroll
        for (int mb = 0; mb < 4; ++mb)
#pragma unroll
            for (int nb = 0; nb < 2; ++nb)
#pragma unroll
                for (int r = 0; r < 4; ++r) {
                    int row = mb * 16 + orr + r;
                    int col = nb * 16 + oc;
                    wlds[row * 32 + (col ^ (((row >> 2) & 3) << 3))] = f2bf(acc[mb][nb][r]);
                }
        asm volatile("s_waitcnt lgkmcnt(0)" ::: "memory");   // wave-private, no barrier
        uint16_t* pb = P + (size_t)sk * OUT_N
                         + (size_t)(mt * 128 + wr * 64) * O_DIM + nt * 128 + wc * 32;
#pragma unroll
        for (int j = 0; j < 4; ++j) {
            int c   = j * 64 + lane;
            int row = c >> 2;
            int u   = (c & 3) * 8;
            uint4 v = *(const uint4*)&wlds[row * 32 + (u ^ (((row >> 2) & 3) << 3))];
            *(uint4*)(pb + (size_t)row * O_DIM + u) = v;
        }
    } else {
        float* ob = out + (size_t)(mt * 128 + wr * 64) * O_DIM + nt * 128 + wc * 32;
#pragma unroll
        for (int mb = 0; mb < 4; ++mb)
#pragma unroll
            for (int nb = 0; nb < 2; ++nb)
#pragma unroll
                for (int r = 0; r < 4; ++r)
                    atomicAdd(&ob[(size_t)(mb * 16 + orr + r) * O_DIM + nb * 16 + oc],
                              acc[mb][nb][r]);
    }
}

// ---------------- reduce: out[j] = sum_sk bf2f(P[sk][j]) ----------------
__global__ void reduce_kernel(const uint16_t* __restrict__ P, float* __restrict__ out) {
    size_t idx = ((size_t)blockIdx.x * 256 + threadIdx.x) * 8;
    float s[8] = {0, 0, 0, 0, 0, 0, 0, 0};
#pragma unroll
    for (int sk = 0; sk < SPLITK; ++sk) {
        uint4 v = *(const uint4*)(P + (size_t)sk * OUT_N + idx);
        uint32_t w[4] = {v.x, v.y, v.z, v.w};
#pragma unroll
        for (int j = 0; j < 4; ++j) {
            s[2 * j]     += bf2f((w[j] & 0xFFFFu) << 16);
            s[2 * j + 1] += bf2f(w[j] & 0xFFFF0000u);
        }
    }
    float4 lo = {s[0], s[1], s[2], s[3]};
    float4 hi = {s[4], s[5], s[6], s[7]};
    *(float4*)(out + idx)     = lo;
    *(float4*)(out + idx + 4) = hi;
}

extern "C" void kernel_launch(void* const* d_in, const int* in_sizes, int n_in,
                              void* d_out, int out_size, void* d_ws, size_t ws_size,
                              hipStream_t stream) {
    const float* x      = (const float*)d_in[0];
    const float* coeffs = (const float*)d_in[1];
    const float* imp    = (const float*)d_in[2];
    float* out = (float*)d_out;

    const size_t A_ELEMS  = (size_t)B_DIM * KD;          // 16,777,216 (33.6 MB)
    const size_t WT_ELEMS = (size_t)O_DIM * KD;          //  4,194,304 ( 8.4 MB)
    const size_t P_ELEMS  = (size_t)SPLITK * OUT_N;      //  8,388,608 (16.8 MB)
    uint16_t* A  = (uint16_t*)d_ws;
    uint16_t* WT = A + A_ELEMS;
    uint16_t* P  = WT + WT_ELEMS;
    const size_t need = (A_ELEMS + WT_ELEMS + P_ELEMS) * 2;   // ~58.7 MB

    hipLaunchKernelGGL(prep_kernel, dim3(512 + 128), dim3(256), 0, stream,
                       x, coeffs, imp, A, WT);
    if (ws_size >= need) {
        hipLaunchKernelGGL((gemm_kernel<1>), dim3(512), dim3(512), 0, stream, A, WT, out, P);
        hipLaunchKernelGGL(reduce_kernel, dim3(OUT_N / 8 / 256), dim3(256), 0, stream, P, out);
    } else {
        hipLaunchKernelGGL(zero_kernel, dim3((OUT_N / 4) / 256), dim3(256), 0, stream,
                           (float4*)out, OUT_N / 4);
        hipLaunchKernelGGL((gemm_kernel<0>), dim3(512), dim3(512), 0, stream, A, WT, out, P);
    }
}